// Round 20
// baseline (72.057 us; speedup 1.0000x reference)
//
#include <hip/hip_runtime.h>
#include <math.h>

#define BB 64
#define SS 2048
#define DD 512
#define NU 512
#define WIN 128
#define G_OFF   0
#define ST_OFF  64
#define EN_OFF  128
#define M_OFF   256                  // [64][32] block-local max
#define S_OFF   (256 + BB * 32)      // [64][32] block-local exp-sum

__device__ __forceinline__ float wave_reduce_sum(float v) {
    #pragma unroll
    for (int off = 32; off > 0; off >>= 1)
        v += __shfl_down(v, off, 64);
    return v;
}

__device__ __forceinline__ float wave_reduce_max(float v) {
    #pragma unroll
    for (int off = 32; off > 0; off >>= 1)
        v = fmaxf(v, __shfl_down(v, off, 64));
    return v;
}

__device__ __forceinline__ float dot4(const float4 a, const float4 b) {
    return a.x * b.x + a.y * b.y + a.z * b.z + a.w * b.w;
}

// Kernel 1 (identical to R19).
// Blocks [0, 64): p-path (16-lane-group GEMV over Wq).
// Blocks [64, 64+2048): score, 64 rows/block, 4 passes, 2-deep pipeline;
//   each block also writes its local softmax stats (m_i, sum_i).
__global__ __launch_bounds__(256, 4) void score_p_kernel(const float* __restrict__ query,
                                                         const float* __restrict__ keys,
                                                         const int* __restrict__ key_lengths,
                                                         const float* __restrict__ Wq,
                                                         const float* __restrict__ wp,
                                                         float* __restrict__ score,
                                                         float* __restrict__ ws) {
    const int t    = threadIdx.x;
    const int wave = t >> 6;
    const int lane = t & 63;
    const int g    = lane >> 4;   // 4 rows per wave pass
    const int w    = lane & 15;   // 16 lanes span one 512-float row

    if (blockIdx.x < BB) {
        // ---- p path: one block per batch ----
        const int b = blockIdx.x;
        __shared__ float act[NU];
        __shared__ float wsum[4];

        const float4* qv = (const float4*)(query + b * DD);
        const float4 q0 = qv[w],       q1 = qv[16 + w],  q2 = qv[32 + w],  q3 = qv[48 + w];
        const float4 q4 = qv[64 + w],  q5 = qv[80 + w],  q6 = qv[96 + w],  q7 = qv[112 + w];

        #pragma unroll 2
        for (int pass = 0; pass < 32; ++pass) {
            const int u = pass * 16 + wave * 4 + g;
            const float4* rv = (const float4*)(Wq + (size_t)u * DD);
            const float4 k0 = rv[w],       k1 = rv[16 + w],  k2 = rv[32 + w],  k3 = rv[48 + w];
            const float4 k4 = rv[64 + w],  k5 = rv[80 + w],  k6 = rv[96 + w],  k7 = rv[112 + w];
            const float s0 = dot4(k0, q0), s1 = dot4(k1, q1), s2 = dot4(k2, q2), s3 = dot4(k3, q3);
            const float s4 = dot4(k4, q4), s5 = dot4(k5, q5), s6 = dot4(k6, q6), s7 = dot4(k7, q7);
            float acc = ((s0 + s1) + (s2 + s3)) + ((s4 + s5) + (s6 + s7));
            #pragma unroll
            for (int m = 1; m < 16; m <<= 1)
                acc += __shfl_xor(acc, m, 64);
            if (w == 0) act[u] = tanhf(acc);
        }
        __syncthreads();

        float sv = act[t] * wp[t] + act[t + 256] * wp[t + 256];
        sv = wave_reduce_sum(sv);
        if (lane == 0) wsum[wave] = sv;
        __syncthreads();

        if (t == 0) {
            const float s = wsum[0] + wsum[1] + wsum[2] + wsum[3];
            const float sig = 1.0f / (1.0f + expf(-s));
            const float L = (float)key_lengths[b];
            const float p = L * sig;
            const int start = (int)(p - (float)WIN);   // trunc toward zero
            const int end   = (int)(p + (float)WIN);
            const float diff = L - p;
            const float gg = expf(-(diff * diff) / (float)WIN);
            ws[G_OFF + b] = gg;
            ((int*)ws)[ST_OFF + b] = start;
            ((int*)ws)[EN_OFF + b] = end;
        }
    } else {
        // ---- score path: software-pipelined 16-lane-group GEMV ----
        const int bid   = blockIdx.x - BB;
        const int b     = bid >> 5;   // 32 blocks per batch
        const int chunk = bid & 31;   // 64 rows per block
        const int r0    = chunk * 64 + wave * 16;
        __shared__ float sc_l[64];

        const float4* qv = (const float4*)(query + b * DD);
        const float4 q0 = qv[w],       q1 = qv[16 + w],  q2 = qv[32 + w],  q3 = qv[48 + w];
        const float4 q4 = qv[64 + w],  q5 = qv[80 + w],  q6 = qv[96 + w],  q7 = qv[112 + w];

        const float4* kb = (const float4*)(keys + (size_t)b * SS * DD);

        // prologue: load pass 0
        const float4* rv = kb + (size_t)(r0 + g) * (DD / 4);
        float4 k0 = rv[w],       k1 = rv[16 + w],  k2 = rv[32 + w],  k3 = rv[48 + w];
        float4 k4 = rv[64 + w],  k5 = rv[80 + w],  k6 = rv[96 + w],  k7 = rv[112 + w];

        #pragma unroll
        for (int p = 0; p < 4; ++p) {
            float4 n0, n1, n2, n3, n4, n5, n6, n7;
            if (p < 3) {   // issue next pass's loads before this pass's reduce
                const float4* nv = kb + (size_t)(r0 + (p + 1) * 4 + g) * (DD / 4);
                n0 = nv[w];       n1 = nv[16 + w];  n2 = nv[32 + w];  n3 = nv[48 + w];
                n4 = nv[64 + w];  n5 = nv[80 + w];  n6 = nv[96 + w];  n7 = nv[112 + w];
            }
            const float s0 = dot4(k0, q0), s1 = dot4(k1, q1), s2 = dot4(k2, q2), s3 = dot4(k3, q3);
            const float s4 = dot4(k4, q4), s5 = dot4(k5, q5), s6 = dot4(k6, q6), s7 = dot4(k7, q7);
            float acc = ((s0 + s1) + (s2 + s3)) + ((s4 + s5) + (s6 + s7));
            #pragma unroll
            for (int m = 1; m < 16; m <<= 1)
                acc += __shfl_xor(acc, m, 64);
            if (w == 0) {
                score[b * SS + r0 + p * 4 + g] = acc;
                sc_l[wave * 16 + p * 4 + g] = acc;
            }
            if (p < 3) {
                k0 = n0; k1 = n1; k2 = n2; k3 = n3;
                k4 = n4; k5 = n5; k6 = n6; k7 = n7;
            }
        }
        __syncthreads();

        // block-local softmax stats over the 64 scores (wave 0 only)
        if (t < 64) {
            const float v = sc_l[t];
            float m = wave_reduce_max(v);
            const float mloc = __shfl(m, 0, 64);
            const float ssum = wave_reduce_sum(expf(v - mloc));
            if (t == 0) {
                ws[M_OFF + b * 32 + chunk] = mloc;
                ws[S_OFF + b * 32 + chunk] = ssum;
            }
        }
    }
}

// Kernel 2: d-split context. grid (B, 4) x 512: block owns 128 d-columns and
// walks the whole window; thread (r = t>>7, c = t&127) accumulates rows
// r, r+4, ... -> 4 rows in flight, 256 B contiguous per wave. Each (b,d) is
// written by exactly one block: no partials, no second stage, deterministic.
__global__ __launch_bounds__(512) void ctx_kernel(const float* __restrict__ keys,
                                                  const float* __restrict__ score,
                                                  const float* __restrict__ ws,
                                                  float* __restrict__ ctx) {
    const int b      = blockIdx.x;
    const int dchunk = blockIdx.y;
    const int t      = threadIdx.x;
    const int wave   = t >> 6;
    const int lane   = t & 63;

    __shared__ float w_lds[260];
    __shared__ float stat_l[2];
    __shared__ float part_l[3][128];

    // merge per-chunk (m_i, s_i): mx = max m_i; tot = sum s_i * exp(m_i - mx)
    if (wave == 0) {
        const float mi = (lane < 32) ? ws[M_OFF + b * 32 + lane] : -INFINITY;
        float m = wave_reduce_max(mi);
        const float mx0 = __shfl(m, 0, 64);
        const float si = (lane < 32) ? ws[S_OFF + b * 32 + lane] * expf(mi - mx0) : 0.f;
        float s = wave_reduce_sum(si);
        if (lane == 0) { stat_l[0] = mx0; stat_l[1] = 1.0f / s; }
    }
    __syncthreads();
    const float mx  = stat_l[0];
    const float inv = stat_l[1];

    const float gg   = ws[G_OFF + b];
    const int start  = ((const int*)ws)[ST_OFF + b];
    const int end    = ((const int*)ws)[EN_OFF + b];
    const int s_lo   = max(start, 0);
    const int s_hi   = min(end, SS);
    const int width  = s_hi - s_lo;              // in [0, 257]

    const float* srow = score + b * SS;
    for (int i = t; i < width; i += 512)
        w_lds[i] = expf(srow[s_lo + i] - mx) * inv * gg;
    __syncthreads();

    // window walk: 4 rows in flight, 128 contiguous columns per block
    const int r  = t >> 7;          // 0..3
    const int c  = t & 127;
    const float* kb = keys + ((size_t)b * SS + s_lo) * DD + dchunk * 128;

    float acc = 0.f;
    for (int i = r; i < width; i += 4)
        acc += w_lds[i] * kb[(size_t)i * DD + c];

    if (r) part_l[r - 1][c] = acc;
    __syncthreads();
    if (r == 0) {
        #pragma unroll
        for (int j = 0; j < 3; ++j) acc += part_l[j][c];
        ctx[b * DD + dchunk * 128 + c] = acc;
    }
}

extern "C" void kernel_launch(void* const* d_in, const int* in_sizes, int n_in,
                              void* d_out, int out_size, void* d_ws, size_t ws_size,
                              hipStream_t stream) {
    const float* query       = (const float*)d_in[0];
    const float* keys        = (const float*)d_in[1];
    const int*   key_lengths = (const int*)d_in[2];
    const float* Wq          = (const float*)d_in[3];
    const float* wp          = (const float*)d_in[4];

    float* ctx   = (float*)d_out;             // [64, 512]
    float* score = (float*)d_out + BB * DD;   // [64, 2048]
    float* ws    = (float*)d_ws;              // {g, start, end, m[64][32], s[64][32]}

    hipLaunchKernelGGL(score_p_kernel, dim3(BB + BB * 32), dim3(256), 0, stream,
                       query, keys, key_lengths, Wq, wp, score, ws);
    hipLaunchKernelGGL(ctx_kernel, dim3(BB, 4), dim3(512), 0, stream,
                       keys, score, ws, ctx);
}

// Round 21
// 62.393 us; speedup vs baseline: 1.1549x; 1.1549x over previous
//
#include <hip/hip_runtime.h>
#include <math.h>

#define BB 64
#define SS 2048
#define DD 512
#define NU 512
#define WIN 128
#define NSLICE 8
#define G_OFF   0
#define ST_OFF  64
#define EN_OFF  128
#define M_OFF   256                  // [64][32] block-local max
#define S_OFF   (256 + BB * 32)      // [64][32] block-local exp-sum
#define PART_OFF 8192                // float offset of partials inside d_ws

__device__ __forceinline__ float wave_reduce_sum(float v) {
    #pragma unroll
    for (int off = 32; off > 0; off >>= 1)
        v += __shfl_down(v, off, 64);
    return v;
}

__device__ __forceinline__ float wave_reduce_max(float v) {
    #pragma unroll
    for (int off = 32; off > 0; off >>= 1)
        v = fmaxf(v, __shfl_down(v, off, 64));
    return v;
}

__device__ __forceinline__ float dot4(const float4 a, const float4 b) {
    return a.x * b.x + a.y * b.y + a.z * b.z + a.w * b.w;
}

// Kernel 1 (identical to R19).
// Blocks [0, 64): p-path (16-lane-group GEMV over Wq).
// Blocks [64, 64+2048): score, 64 rows/block, 4 passes, 2-deep pipeline;
//   each block also writes its local softmax stats (m_i, sum_i).
__global__ __launch_bounds__(256, 4) void score_p_kernel(const float* __restrict__ query,
                                                         const float* __restrict__ keys,
                                                         const int* __restrict__ key_lengths,
                                                         const float* __restrict__ Wq,
                                                         const float* __restrict__ wp,
                                                         float* __restrict__ score,
                                                         float* __restrict__ ws) {
    const int t    = threadIdx.x;
    const int wave = t >> 6;
    const int lane = t & 63;
    const int g    = lane >> 4;   // 4 rows per wave pass
    const int w    = lane & 15;   // 16 lanes span one 512-float row

    if (blockIdx.x < BB) {
        // ---- p path: one block per batch ----
        const int b = blockIdx.x;
        __shared__ float act[NU];
        __shared__ float wsum[4];

        const float4* qv = (const float4*)(query + b * DD);
        const float4 q0 = qv[w],       q1 = qv[16 + w],  q2 = qv[32 + w],  q3 = qv[48 + w];
        const float4 q4 = qv[64 + w],  q5 = qv[80 + w],  q6 = qv[96 + w],  q7 = qv[112 + w];

        #pragma unroll 2
        for (int pass = 0; pass < 32; ++pass) {
            const int u = pass * 16 + wave * 4 + g;
            const float4* rv = (const float4*)(Wq + (size_t)u * DD);
            const float4 k0 = rv[w],       k1 = rv[16 + w],  k2 = rv[32 + w],  k3 = rv[48 + w];
            const float4 k4 = rv[64 + w],  k5 = rv[80 + w],  k6 = rv[96 + w],  k7 = rv[112 + w];
            const float s0 = dot4(k0, q0), s1 = dot4(k1, q1), s2 = dot4(k2, q2), s3 = dot4(k3, q3);
            const float s4 = dot4(k4, q4), s5 = dot4(k5, q5), s6 = dot4(k6, q6), s7 = dot4(k7, q7);
            float acc = ((s0 + s1) + (s2 + s3)) + ((s4 + s5) + (s6 + s7));
            #pragma unroll
            for (int m = 1; m < 16; m <<= 1)
                acc += __shfl_xor(acc, m, 64);
            if (w == 0) act[u] = tanhf(acc);
        }
        __syncthreads();

        float sv = act[t] * wp[t] + act[t + 256] * wp[t + 256];
        sv = wave_reduce_sum(sv);
        if (lane == 0) wsum[wave] = sv;
        __syncthreads();

        if (t == 0) {
            const float s = wsum[0] + wsum[1] + wsum[2] + wsum[3];
            const float sig = 1.0f / (1.0f + expf(-s));
            const float L = (float)key_lengths[b];
            const float p = L * sig;
            const int start = (int)(p - (float)WIN);   // trunc toward zero
            const int end   = (int)(p + (float)WIN);
            const float diff = L - p;
            const float gg = expf(-(diff * diff) / (float)WIN);
            ws[G_OFF + b] = gg;
            ((int*)ws)[ST_OFF + b] = start;
            ((int*)ws)[EN_OFF + b] = end;
        }
    } else {
        // ---- score path: software-pipelined 16-lane-group GEMV ----
        const int bid   = blockIdx.x - BB;
        const int b     = bid >> 5;   // 32 blocks per batch
        const int chunk = bid & 31;   // 64 rows per block
        const int r0    = chunk * 64 + wave * 16;
        __shared__ float sc_l[64];

        const float4* qv = (const float4*)(query + b * DD);
        const float4 q0 = qv[w],       q1 = qv[16 + w],  q2 = qv[32 + w],  q3 = qv[48 + w];
        const float4 q4 = qv[64 + w],  q5 = qv[80 + w],  q6 = qv[96 + w],  q7 = qv[112 + w];

        const float4* kb = (const float4*)(keys + (size_t)b * SS * DD);

        // prologue: load pass 0
        const float4* rv = kb + (size_t)(r0 + g) * (DD / 4);
        float4 k0 = rv[w],       k1 = rv[16 + w],  k2 = rv[32 + w],  k3 = rv[48 + w];
        float4 k4 = rv[64 + w],  k5 = rv[80 + w],  k6 = rv[96 + w],  k7 = rv[112 + w];

        #pragma unroll
        for (int p = 0; p < 4; ++p) {
            float4 n0, n1, n2, n3, n4, n5, n6, n7;
            if (p < 3) {   // issue next pass's loads before this pass's reduce
                const float4* nv = kb + (size_t)(r0 + (p + 1) * 4 + g) * (DD / 4);
                n0 = nv[w];       n1 = nv[16 + w];  n2 = nv[32 + w];  n3 = nv[48 + w];
                n4 = nv[64 + w];  n5 = nv[80 + w];  n6 = nv[96 + w];  n7 = nv[112 + w];
            }
            const float s0 = dot4(k0, q0), s1 = dot4(k1, q1), s2 = dot4(k2, q2), s3 = dot4(k3, q3);
            const float s4 = dot4(k4, q4), s5 = dot4(k5, q5), s6 = dot4(k6, q6), s7 = dot4(k7, q7);
            float acc = ((s0 + s1) + (s2 + s3)) + ((s4 + s5) + (s6 + s7));
            #pragma unroll
            for (int m = 1; m < 16; m <<= 1)
                acc += __shfl_xor(acc, m, 64);
            if (w == 0) {
                score[b * SS + r0 + p * 4 + g] = acc;
                sc_l[wave * 16 + p * 4 + g] = acc;
            }
            if (p < 3) {
                k0 = n0; k1 = n1; k2 = n2; k3 = n3;
                k4 = n4; k5 = n5; k6 = n6; k7 = n7;
            }
        }
        __syncthreads();

        // block-local softmax stats over the 64 scores (wave 0 only)
        if (t < 64) {
            const float v = sc_l[t];
            float m = wave_reduce_max(v);
            const float mloc = __shfl(m, 0, 64);
            const float ssum = wave_reduce_sum(expf(v - mloc));
            if (t == 0) {
                ws[M_OFF + b * 32 + chunk] = mloc;
                ws[S_OFF + b * 32 + chunk] = ssum;
            }
        }
    }
}

// Kernel 2 (stage A): merge 32 block-local stats (exact), then windowed
// weighted key sum over a contiguous slice. 512 threads, 4 rows in flight.
// NSLICE=8: each block walks only ~8 dependent 4-row steps.
__global__ __launch_bounds__(512) void ctxA_kernel(const float* __restrict__ keys,
                                                   const float* __restrict__ score,
                                                   const float* __restrict__ ws,
                                                   float* __restrict__ part) {
    const int b     = blockIdx.x;
    const int slice = blockIdx.y;
    const int t     = threadIdx.x;
    const int wave  = t >> 6;
    const int lane  = t & 63;

    __shared__ float w_lds[40];
    __shared__ float stat_l[2];
    __shared__ float4 part_l[3][128];

    // merge per-chunk (m_i, s_i): mx = max m_i; tot = sum s_i * exp(m_i - mx)
    if (wave == 0) {
        const float mi = (lane < 32) ? ws[M_OFF + b * 32 + lane] : -INFINITY;
        float m = wave_reduce_max(mi);
        const float mx0 = __shfl(m, 0, 64);
        const float si = (lane < 32) ? ws[S_OFF + b * 32 + lane] * expf(mi - mx0) : 0.f;
        float s = wave_reduce_sum(si);
        if (lane == 0) { stat_l[0] = mx0; stat_l[1] = 1.0f / s; }
    }
    __syncthreads();
    const float mx  = stat_l[0];
    const float inv = stat_l[1];

    const float gg   = ws[G_OFF + b];
    const int start  = ((const int*)ws)[ST_OFF + b];
    const int end    = ((const int*)ws)[EN_OFF + b];
    const int s_lo   = max(start, 0);
    const int s_hi   = min(end, SS);
    const int width  = s_hi - s_lo;              // in [0, 257]
    const int sliceN = (width + NSLICE - 1) / NSLICE;
    const int i_lo   = slice * sliceN;
    const int i_hi   = min(i_lo + sliceN, width);
    const int n      = i_hi - i_lo;              // may be <= 0

    const float* srow = score + b * SS;
    for (int i = t; i < n; i += 512)
        w_lds[i] = expf(srow[s_lo + i_lo + i] - mx) * inv * gg;
    __syncthreads();

    // linear stream: 4 rows x 128 float4-cols per step, thread owns col group c4
    const int myrow = t >> 7;        // 0..3
    const int c4    = t & 127;
    const float4* kb = (const float4*)(keys + ((size_t)b * SS + s_lo + i_lo) * DD);

    float4 acc = make_float4(0.f, 0.f, 0.f, 0.f);
    for (int i = myrow; i < n; i += 4) {
        const float4 k = kb[(size_t)i * (DD / 4) + c4];
        const float wg = w_lds[i];
        acc.x += wg * k.x; acc.y += wg * k.y; acc.z += wg * k.z; acc.w += wg * k.w;
    }

    if (myrow) part_l[myrow - 1][c4] = acc;
    __syncthreads();
    if (myrow == 0) {
        #pragma unroll
        for (int r = 0; r < 3; ++r) {
            const float4 o = part_l[r][c4];
            acc.x += o.x; acc.y += o.y; acc.z += o.z; acc.w += o.w;
        }
        ((float4*)part)[((size_t)b * NSLICE + slice) * 128 + c4] = acc;
    }
}

// Kernel 2 (stage B): ctx[b][d] = sum over slices of partials
__global__ __launch_bounds__(512) void ctxB_kernel(const float* __restrict__ part,
                                                   float* __restrict__ ctx) {
    const int b = blockIdx.x;
    const int d = threadIdx.x;
    float s = 0.f;
    #pragma unroll
    for (int sl = 0; sl < NSLICE; ++sl)
        s += part[((size_t)b * NSLICE + sl) * DD + d];
    ctx[b * DD + d] = s;
}

extern "C" void kernel_launch(void* const* d_in, const int* in_sizes, int n_in,
                              void* d_out, int out_size, void* d_ws, size_t ws_size,
                              hipStream_t stream) {
    const float* query       = (const float*)d_in[0];
    const float* keys        = (const float*)d_in[1];
    const int*   key_lengths = (const int*)d_in[2];
    const float* Wq          = (const float*)d_in[3];
    const float* wp          = (const float*)d_in[4];

    float* ctx   = (float*)d_out;             // [64, 512]
    float* score = (float*)d_out + BB * DD;   // [64, 2048]
    float* ws    = (float*)d_ws;              // {g, start, end, m[64][32], s[64][32]}
    float* part  = (float*)d_ws + PART_OFF;   // [64, NSLICE, 512]

    hipLaunchKernelGGL(score_p_kernel, dim3(BB + BB * 32), dim3(256), 0, stream,
                       query, keys, key_lengths, Wq, wp, score, ws);
    hipLaunchKernelGGL(ctxA_kernel, dim3(BB, NSLICE), dim3(512), 0, stream,
                       keys, score, ws, part);
    hipLaunchKernelGGL(ctxB_kernel, dim3(BB), dim3(512), 0, stream,
                       part, ctx);
}